// Round 4
// baseline (572.669 us; speedup 1.0000x reference)
//
#include <hip/hip_runtime.h>
#include <hip/hip_bf16.h>

#define BB 2
#define HH 16
#define SS 2048
#define DD 128

constexpr int BM = 64;   // q rows per block
constexpr int BN = 64;   // kv cols per tile
constexpr int NW = 4;    // waves per block
constexpr int QSTR = DD + 8;   // 136
constexpr int PSTR = BN + 8;   // 72
constexpr size_t SD = (size_t)SS * DD;                    // 262144
constexpr size_t KV_ELEMS = (size_t)BB * HH * SS * DD;    // 8388608

typedef __bf16 bf16_t;
typedef __attribute__((ext_vector_type(8))) __bf16 bf16x8;
typedef __attribute__((ext_vector_type(4))) __bf16 bf16x4;
typedef __attribute__((ext_vector_type(4))) float floatx4;

// ---------------- fused pre-pass: K fp32->bf16 copy, V fp32->bf16 transpose ----------------
__global__ __launch_bounds__(256)
void prep_kv(const float* __restrict__ kp, const float* __restrict__ vp,
             bf16_t* __restrict__ kbf, bf16_t* __restrict__ vtbf)
{
    const int tid  = threadIdx.x;
    const int lane = tid & 63;
    const int w    = tid >> 6;
    const int kv0  = blockIdx.x * BN;
    const size_t bh = blockIdx.y;

    const float* kb = kp + bh * SD;
    const float* vb = vp + bh * SD;
    bf16_t* ko = kbf  + bh * SD;
    bf16_t* vo = vtbf + bh * (size_t)DD * SS;

    #pragma unroll
    for (int i = 0; i < 8; ++i) {
        int idx4 = tid + i * 256;
        int row  = idx4 >> 5;
        int c4   = idx4 & 31;
        float4 val = *reinterpret_cast<const float4*>(kb + (size_t)(kv0 + row) * DD + c4 * 4);
        bf16x4 o;
        o[0] = (bf16_t)val.x; o[1] = (bf16_t)val.y; o[2] = (bf16_t)val.z; o[3] = (bf16_t)val.w;
        *reinterpret_cast<bf16x4*>(ko + (size_t)(kv0 + row) * DD + c4 * 4) = o;
    }

    const int kv = kv0 + lane;
    #pragma unroll
    for (int i = 0; i < 8; ++i) {
        int d = w * 32 + i * 4;
        float4 val = *reinterpret_cast<const float4*>(vb + (size_t)kv * DD + d);
        vo[(size_t)(d + 0) * SS + kv] = (bf16_t)val.x;
        vo[(size_t)(d + 1) * SS + kv] = (bf16_t)val.y;
        vo[(size_t)(d + 2) * SS + kv] = (bf16_t)val.z;
        vo[(size_t)(d + 3) * SS + kv] = (bf16_t)val.w;
    }
}

// ------------- main kernel: barrier-free K-loop, register-direct KV fragments -------------
__global__ __launch_bounds__(256, 3)
void flexattn_fwd_bf16(const float* __restrict__ qp, const bf16_t* __restrict__ kbf,
                       const bf16_t* __restrict__ vtbf, float* __restrict__ op)
{
    __shared__ __align__(16) bf16_t QPu[BM * QSTR];        // 17408 B: Q tile, then P
    bf16_t (*Qs)[QSTR]     = reinterpret_cast<bf16_t(*)[QSTR]>(&QPu[0]);
    bf16_t (*Ps)[16][PSTR] = reinterpret_cast<bf16_t(*)[16][PSTR]>(&QPu[0]);

    const int tid  = threadIdx.x;
    const int wave = tid >> 6;
    const int lane = tid & 63;
    const int n16  = lane & 15;
    const int quad = lane >> 4;

    const int qt = gridDim.x - 1 - blockIdx.x;   // heavy blocks dispatch first
    const int bh = blockIdx.y;
    const int h  = bh & (HH - 1);
    const int q0 = qt * BM;

    const float LOG2E  = 1.4426950408889634f;
    const float sscale = 0.08838834764831845f * LOG2E;
    const float slope  = __builtin_amdgcn_exp2f(-8.0f * (float)(h + 1) / (float)HH);
    const float bscale = slope * LOG2E;

    const float*  qb = qp   + (size_t)bh * SD;
    const bf16_t* kb = kbf  + (size_t)bh * SD;
    const bf16_t* vt = vtbf + (size_t)bh * (size_t)DD * SS;
    float*        ob = op   + (size_t)bh * SD;

    // ---- stage Q tile (fp32 -> bf16)
    #pragma unroll
    for (int i = 0; i < 8; ++i) {
        int idx4 = tid + i * 256;
        int row  = idx4 >> 5;
        int c4   = idx4 & 31;
        const float4 val = *reinterpret_cast<const float4*>(qb + (size_t)(q0 + row) * DD + c4 * 4);
        bf16x4 w;
        w[0] = (bf16_t)val.x; w[1] = (bf16_t)val.y; w[2] = (bf16_t)val.z; w[3] = (bf16_t)val.w;
        *reinterpret_cast<bf16x4*>(&Qs[row][c4 * 4]) = w;
    }
    __syncthreads();

    bf16x8 qf[4];   // B-operand: B[k=d][n=q=n16]
    #pragma unroll
    for (int c = 0; c < 4; ++c)
        qf[c] = *reinterpret_cast<const bf16x8*>(&Qs[wave * 16 + n16][c * 32 + quad * 8]);
    __syncthreads();   // all qf reads done before any wave writes P into QPu

    floatx4 o[8];
    #pragma unroll
    for (int t = 0; t < 8; ++t) o[t] = (floatx4){0.f, 0.f, 0.f, 0.f};
    float m_i = -3.0e38f, l_i = 0.f;

    const int bias_base = quad * 4 - (q0 + wave * 16 + n16);

    // fragment base pointers (lane-fixed part)
    const bf16_t* kfb = kb + (size_t)n16 * DD + quad * 8;   // + kv_local*DD + c*32
    const bf16_t* vfb = vt + (size_t)n16 * SS + quad * 8;   // + d_tile*16*SS + kv0 + c*32

    // ---- prefetch nt=0 K-fragments for kt=0
    bf16x8 kf0[4];
    #pragma unroll
    for (int c = 0; c < 4; ++c)
        kf0[c] = *reinterpret_cast<const bf16x8*>(kfb + c * 32);

    for (int kt = 0; kt <= qt; ++kt) {
        const int kv0 = kt * BN;
        const bf16_t* kKt = kfb + (size_t)kv0 * DD;

        // ---- K fragments nt=1..3 (12 x b128 direct from global)
        bf16x8 kf[3][4];
        #pragma unroll
        for (int nt = 1; nt < 4; ++nt)
            #pragma unroll
            for (int c = 0; c < 4; ++c)
                kf[nt - 1][c] = *reinterpret_cast<const bf16x8*>(kKt + (size_t)(nt * 16) * DD + c * 32);

        // ---- S^T = K * Q^T
        floatx4 sc[4];
        {
            floatx4 acc = (floatx4){0.f, 0.f, 0.f, 0.f};
            #pragma unroll
            for (int c = 0; c < 4; ++c)
                acc = __builtin_amdgcn_mfma_f32_16x16x32_bf16(kf0[c], qf[c], acc, 0, 0, 0);
            sc[0] = acc;
        }
        #pragma unroll
        for (int nt = 1; nt < 4; ++nt) {
            floatx4 acc = (floatx4){0.f, 0.f, 0.f, 0.f};
            #pragma unroll
            for (int c = 0; c < 4; ++c)
                acc = __builtin_amdgcn_mfma_f32_16x16x32_bf16(kf[nt - 1][c], qf[c], acc, 0, 0, 0);
            sc[nt] = acc;
        }

        // ---- V fragments t=0..3, issued here so softmax covers their latency
        bf16x8 vfa[4][2];
        #pragma unroll
        for (int t = 0; t < 4; ++t)
            #pragma unroll
            for (int c = 0; c < 2; ++c)
                vfa[t][c] = *reinterpret_cast<const bf16x8*>(vfb + (size_t)(t * 16) * SS + kv0 + c * 32);

        // ---- scale + ALiBi + causal; per-lane row stats + 2 shuffles
        const bool diag = (kt == qt);
        float mloc = -3.0e38f;
        #pragma unroll
        for (int nt = 0; nt < 4; ++nt) {
            #pragma unroll
            for (int r = 0; r < 4; ++r) {
                int delta = kv0 + nt * 16 + r + bias_base;
                float sval = sc[nt][r] * sscale + bscale * (float)delta;
                if (diag && delta > 0) sval = -3.0e38f;
                sc[nt][r] = sval;
                mloc = fmaxf(mloc, sval);
            }
        }
        mloc = fmaxf(mloc, __shfl_xor(mloc, 16));
        mloc = fmaxf(mloc, __shfl_xor(mloc, 32));

        const float mnew  = fmaxf(m_i, mloc);
        const float alpha = __builtin_amdgcn_exp2f(m_i - mnew);
        m_i = mnew;

        float rs = 0.f;
        #pragma unroll
        for (int nt = 0; nt < 4; ++nt) {
            #pragma unroll
            for (int r = 0; r < 4; ++r) {
                float p = __builtin_amdgcn_exp2f(sc[nt][r] - mnew);
                sc[nt][r] = p;
                rs += p;
            }
        }
        rs += __shfl_xor(rs, 16);
        rs += __shfl_xor(rs, 32);
        l_i = l_i * alpha + rs;

        // ---- P^T -> LDS, permuted col s = quad*16 + nt*4 + r (2x b128, wave-private)
        bf16x8 p0, p1;
        #pragma unroll
        for (int r = 0; r < 4; ++r) {
            p0[r]     = (bf16_t)sc[0][r];
            p0[r + 4] = (bf16_t)sc[1][r];
            p1[r]     = (bf16_t)sc[2][r];
            p1[r + 4] = (bf16_t)sc[3][r];
        }
        *reinterpret_cast<bf16x8*>(&Ps[wave][n16][quad * 16])     = p0;
        *reinterpret_cast<bf16x8*>(&Ps[wave][n16][quad * 16 + 8]) = p1;

        // ---- V fragments t=4..7 (latency covered by P round-trip + PV t=0..3)
        bf16x8 vfb2[4][2];
        #pragma unroll
        for (int t = 0; t < 4; ++t)
            #pragma unroll
            for (int c = 0; c < 2; ++c)
                vfb2[t][c] = *reinterpret_cast<const bf16x8*>(vfb + (size_t)((t + 4) * 16) * SS + kv0 + c * 32);

        // ---- prefetch next iteration's nt=0 K-fragments (lands during PV)
        if (kt < qt) {
            const bf16_t* kN = kfb + (size_t)(kv0 + BN) * DD;
            #pragma unroll
            for (int c = 0; c < 4; ++c)
                kf0[c] = *reinterpret_cast<const bf16x8*>(kN + c * 32);
        }

        // ---- rescale O^T
        #pragma unroll
        for (int t = 0; t < 8; ++t) {
            #pragma unroll
            for (int r = 0; r < 4; ++r)
                o[t][r] *= alpha;
        }

        // ---- read P^T as B-fragment: B[k=kv=32c+quad*8+j][n=q=n16]
        bf16x8 pf[2];
        #pragma unroll
        for (int c = 0; c < 2; ++c) {
            #pragma unroll
            for (int j4 = 0; j4 < 2; ++j4) {
                int s0 = (((2 * quad + j4) & 3) * 16) + ((2 * c + (quad >> 1)) * 4);
                bf16x4 ph = *reinterpret_cast<const bf16x4*>(&Ps[wave][n16][s0]);
                pf[c][j4 * 4 + 0] = ph[0];
                pf[c][j4 * 4 + 1] = ph[1];
                pf[c][j4 * 4 + 2] = ph[2];
                pf[c][j4 * 4 + 3] = ph[3];
            }
        }

        // ---- O^T += V^T * P^T
        #pragma unroll
        for (int t = 0; t < 4; ++t) {
            floatx4 acc = o[t];
            #pragma unroll
            for (int c = 0; c < 2; ++c)
                acc = __builtin_amdgcn_mfma_f32_16x16x32_bf16(vfa[t][c], pf[c], acc, 0, 0, 0);
            o[t] = acc;
        }
        #pragma unroll
        for (int t = 0; t < 4; ++t) {
            floatx4 acc = o[t + 4];
            #pragma unroll
            for (int c = 0; c < 2; ++c)
                acc = __builtin_amdgcn_mfma_f32_16x16x32_bf16(vfb2[t][c], pf[c], acc, 0, 0, 0);
            o[t + 4] = acc;
        }
    }

    // ---- epilogue: lane holds q = wave*16+n16, d = t*16 + quad*4 + {0..3} (float4 stores)
    const float inv = 1.0f / l_i;
    const size_t rowoff = (size_t)(q0 + wave * 16 + n16) * DD;
    #pragma unroll
    for (int t = 0; t < 8; ++t) {
        float4 w;
        w.x = o[t][0] * inv; w.y = o[t][1] * inv;
        w.z = o[t][2] * inv; w.w = o[t][3] * inv;
        *reinterpret_cast<float4*>(ob + rowoff + t * 16 + quad * 4) = w;
    }
}

extern "C" void kernel_launch(void* const* d_in, const int* in_sizes, int n_in,
                              void* d_out, int out_size, void* d_ws, size_t ws_size,
                              hipStream_t stream) {
    const float* q = (const float*)d_in[0];
    const float* k = (const float*)d_in[1];
    const float* v = (const float*)d_in[2];
    float* out = (float*)d_out;

    bf16_t* kbf  = (bf16_t*)d_ws;
    bf16_t* vtbf = kbf + KV_ELEMS;
    prep_kv<<<dim3(SS / BN, BB * HH), 256, 0, stream>>>(k, v, kbf, vtbf);
    flexattn_fwd_bf16<<<dim3(SS / BM, BB * HH), 256, 0, stream>>>(q, kbf, vtbf, out);
}

// Round 5
// 245.531 us; speedup vs baseline: 2.3324x; 2.3324x over previous
//
#include <hip/hip_runtime.h>
#include <hip/hip_bf16.h>

#define BB 2
#define HH 16
#define SS 2048
#define DD 128

constexpr int BM = 64;   // q rows per block
constexpr int BN = 64;   // kv cols per tile
constexpr int NW = 4;    // waves per block
constexpr int PSTR = BN + 8;   // 72
constexpr size_t SD = (size_t)SS * DD;                    // 262144
constexpr size_t KV_ELEMS = (size_t)BB * HH * SS * DD;    // 8388608

typedef __bf16 bf16_t;
typedef __attribute__((ext_vector_type(8))) __bf16 bf16x8;
typedef __attribute__((ext_vector_type(4))) __bf16 bf16x4;
typedef __attribute__((ext_vector_type(4))) float floatx4;

__device__ __forceinline__ void dma16(const void* g, void* l) {
    __builtin_amdgcn_global_load_lds(
        (const __attribute__((address_space(1))) unsigned int*)g,
        (__attribute__((address_space(3))) unsigned int*)l,
        16, 0, 0);
}

// ---------------- pre-pass: K fp32->bf16 copy, V fp32->bf16 transpose ----------------
__global__ __launch_bounds__(256)
void prep_kv(const float* __restrict__ kp, const float* __restrict__ vp,
             bf16_t* __restrict__ kbf, bf16_t* __restrict__ vtbf)
{
    const int tid  = threadIdx.x;
    const int lane = tid & 63;
    const int w    = tid >> 6;
    const int kv0  = blockIdx.x * BN;
    const size_t bh = blockIdx.y;

    const float* kb = kp + bh * SD;
    const float* vb = vp + bh * SD;
    bf16_t* ko = kbf  + bh * SD;
    bf16_t* vo = vtbf + bh * (size_t)DD * SS;

    // K: row-major convert, fully coalesced both sides
    #pragma unroll
    for (int i = 0; i < 8; ++i) {
        int idx4 = tid + i * 256;
        int row  = idx4 >> 5;
        int c4   = idx4 & 31;
        float4 val = *reinterpret_cast<const float4*>(kb + (size_t)(kv0 + row) * DD + c4 * 4);
        bf16x4 o;
        o[0] = (bf16_t)val.x; o[1] = (bf16_t)val.y; o[2] = (bf16_t)val.z; o[3] = (bf16_t)val.w;
        *reinterpret_cast<bf16x4*>(ko + (size_t)(kv0 + row) * DD + c4 * 4) = o;
    }

    // V transpose: 16 rows x 64B full-line reads; stores coalesce into 32B segments per quarter-wave
    const int r  = lane >> 2;       // 0..15
    const int cq = lane & 3;        // 0..3
    const int kv = kv0 + w * 16 + r;
    #pragma unroll
    for (int i = 0; i < 8; ++i) {
        int d0 = cq * 4 + i * 16;
        float4 val = *reinterpret_cast<const float4*>(vb + (size_t)kv * DD + d0);
        vo[(size_t)(d0 + 0) * SS + kv] = (bf16_t)val.x;
        vo[(size_t)(d0 + 1) * SS + kv] = (bf16_t)val.y;
        vo[(size_t)(d0 + 2) * SS + kv] = (bf16_t)val.z;
        vo[(size_t)(d0 + 3) * SS + kv] = (bf16_t)val.w;
    }
}

// ------------- main kernel: single-barrier K-loop, DMA double-buffered staging -------------
__global__ __launch_bounds__(256, 2)
void flexattn_fwd_bf16(const float* __restrict__ qp, const bf16_t* __restrict__ kbf,
                       const bf16_t* __restrict__ vtbf, float* __restrict__ op)
{
    // [buf][0]=K tile (64 rows x 256B, XOR-swizzled 16B chunks)
    // [buf][1]=V tile (128 d-rows x 128B, XOR-swizzled 16B chunks)
    __shared__ __align__(16) bf16_t KV[2][2][8192];   // 65536 B
    __shared__ __align__(16) bf16_t QP[8192];         // 16384 B: Q tile (no pad), then P
    bf16_t (*Ps)[16][PSTR] = reinterpret_cast<bf16_t(*)[16][PSTR]>(&QP[0]);

    const int tid  = threadIdx.x;
    const int wave = tid >> 6;
    const int lane = tid & 63;
    const int n16  = lane & 15;
    const int quad = lane >> 4;

    const int qt = gridDim.x - 1 - blockIdx.x;   // heavy blocks dispatch first
    const int bh = blockIdx.y;
    const int h  = bh & (HH - 1);
    const int q0 = qt * BM;

    const float LOG2E  = 1.4426950408889634f;
    const float sscale = 0.08838834764831845f * LOG2E;
    const float slope  = __builtin_amdgcn_exp2f(-8.0f * (float)(h + 1) / (float)HH);
    const float bscale = slope * LOG2E;

    const float*  qb = qp   + (size_t)bh * SD;
    const bf16_t* kb = kbf  + (size_t)bh * SD;
    const bf16_t* vt = vtbf + (size_t)bh * (size_t)DD * SS;
    float*        ob = op   + (size_t)bh * SD;

    // ---- per-lane DMA source offsets (bytes within tile), XOR-swizzled chunk layout
    int koff[4], voff[4];
    #pragma unroll
    for (int i = 0; i < 4; ++i) {
        int c   = wave * 256 + i * 64 + lane;       // chunk index 0..1023
        int kv  = c >> 4;
        int col = (c & 15) ^ (kv & 15);
        koff[i] = kv * 256 + col * 16;              // K: [kv][col*16B]
        int d  = c >> 3;
        int jp = c & 7;
        int j  = jp ^ (d & 7) ^ (((d >> 3) & 1) << 2);
        voff[i] = (d * SS + j * 8) * 2;             // V: [d][kv-chunk j]
    }

    auto dma_tile = [&](int kt, int b) {
        const char* kg = (const char*)kb + (size_t)kt * (BN * DD * 2);
        const char* vg = (const char*)vt + (size_t)kt * (BN * 2);
        char* kl = (char*)&KV[b][0][0];
        char* vl = (char*)&KV[b][1][0];
        #pragma unroll
        for (int i = 0; i < 4; ++i) {
            int base = (wave * 256 + i * 64) * 16;  // wave-uniform LDS byte base
            dma16(kg + koff[i], kl + base);
            dma16(vg + voff[i], vl + base);
        }
    };

    // ---- stage Q tile (fp32 -> bf16), no pad (stride 128 elems)
    #pragma unroll
    for (int i = 0; i < 8; ++i) {
        int idx4 = tid + i * 256;
        int row  = idx4 >> 5;
        int c4   = idx4 & 31;
        const float4 val = *reinterpret_cast<const float4*>(qb + (size_t)(q0 + row) * DD + c4 * 4);
        bf16x4 w;
        w[0] = (bf16_t)val.x; w[1] = (bf16_t)val.y; w[2] = (bf16_t)val.z; w[3] = (bf16_t)val.w;
        *reinterpret_cast<bf16x4*>(&QP[row * 128 + c4 * 4]) = w;
    }
    // ---- DMA tile 0 into buf 0
    dma_tile(0, 0);
    __syncthreads();   // Q staged + DMA(0) drained (implicit vmcnt(0))

    // ---- hoist Q fragments (one-time; unswizzled reads, conflicts are negligible once)
    bf16x8 qf[4];
    #pragma unroll
    for (int c = 0; c < 4; ++c)
        qf[c] = *reinterpret_cast<const bf16x8*>(&QP[(wave * 16 + n16) * 128 + c * 32 + quad * 8]);
    __syncthreads();   // all hoists done before P overwrites QP

    floatx4 o[8];
    #pragma unroll
    for (int t = 0; t < 8; ++t) o[t] = (floatx4){0.f, 0.f, 0.f, 0.f};
    float m_i = -3.0e38f, l_i = 0.f;

    const int bias_base = quad * 4 - (q0 + wave * 16 + n16);

    // ---- fragment LDS byte offsets (swizzle-aware)
    int kfo[4];
    #pragma unroll
    for (int c = 0; c < 4; ++c)
        kfo[c] = n16 * 256 + (((c * 4 + quad) ^ n16) * 16);
    const int vkey = (n16 & 7) ^ (((n16 >> 3) & 1) << 2);
    int vfo[2];
    #pragma unroll
    for (int c = 0; c < 2; ++c)
        vfo[c] = n16 * 128 + (((c * 4 + quad) ^ vkey) * 16);

    for (int kt = 0; kt <= qt; ++kt) {
        const int kv0 = kt * BN;
        const int b   = kt & 1;
        if (kt < qt) dma_tile(kt + 1, b ^ 1);   // lands during compute below

        const char* kl = (const char*)&KV[b][0][0];
        const char* vl = (const char*)&KV[b][1][0];

        // ---- S^T = K * Q^T : sc[nt][r] = S[q = wave*16+n16][kv = kv0 + nt*16 + quad*4 + r]
        floatx4 sc[4];
        #pragma unroll
        for (int nt = 0; nt < 4; ++nt) {
            floatx4 acc = (floatx4){0.f, 0.f, 0.f, 0.f};
            #pragma unroll
            for (int c = 0; c < 4; ++c) {
                bf16x8 kf = *reinterpret_cast<const bf16x8*>(kl + nt * 4096 + kfo[c]);
                acc = __builtin_amdgcn_mfma_f32_16x16x32_bf16(kf, qf[c], acc, 0, 0, 0);
            }
            sc[nt] = acc;
        }

        // ---- scale + ALiBi + causal; per-lane row stats + 2 shuffles
        const bool diag = (kt == qt);
        float mloc = -3.0e38f;
        #pragma unroll
        for (int nt = 0; nt < 4; ++nt) {
            #pragma unroll
            for (int r = 0; r < 4; ++r) {
                int delta = kv0 + nt * 16 + r + bias_base;
                float sval = sc[nt][r] * sscale + bscale * (float)delta;
                if (diag && delta > 0) sval = -3.0e38f;
                sc[nt][r] = sval;
                mloc = fmaxf(mloc, sval);
            }
        }
        mloc = fmaxf(mloc, __shfl_xor(mloc, 16));
        mloc = fmaxf(mloc, __shfl_xor(mloc, 32));

        const float mnew  = fmaxf(m_i, mloc);
        const float alpha = __builtin_amdgcn_exp2f(m_i - mnew);
        m_i = mnew;

        float rs = 0.f;
        #pragma unroll
        for (int nt = 0; nt < 4; ++nt) {
            #pragma unroll
            for (int r = 0; r < 4; ++r) {
                float p = __builtin_amdgcn_exp2f(sc[nt][r] - mnew);
                sc[nt][r] = p;
                rs += p;
            }
        }
        rs += __shfl_xor(rs, 16);
        rs += __shfl_xor(rs, 32);
        l_i = l_i * alpha + rs;

        // ---- P^T -> LDS, permuted col s = quad*16 + nt*4 + r (2x b128, wave-private)
        bf16x8 p0, p1;
        #pragma unroll
        for (int r = 0; r < 4; ++r) {
            p0[r]     = (bf16_t)sc[0][r];
            p0[r + 4] = (bf16_t)sc[1][r];
            p1[r]     = (bf16_t)sc[2][r];
            p1[r + 4] = (bf16_t)sc[3][r];
        }
        *reinterpret_cast<bf16x8*>(&Ps[wave][n16][quad * 16])     = p0;
        *reinterpret_cast<bf16x8*>(&Ps[wave][n16][quad * 16 + 8]) = p1;

        // ---- rescale O^T
        #pragma unroll
        for (int t = 0; t < 8; ++t) {
            #pragma unroll
            for (int r = 0; r < 4; ++r)
                o[t][r] *= alpha;
        }

        // ---- read P^T as B-fragment: B[k=kv=32c+quad*8+j][n=q=n16]
        bf16x8 pf[2];
        #pragma unroll
        for (int c = 0; c < 2; ++c) {
            #pragma unroll
            for (int j4 = 0; j4 < 2; ++j4) {
                int s0 = (((2 * quad + j4) & 3) * 16) + ((2 * c + (quad >> 1)) * 4);
                bf16x4 ph = *reinterpret_cast<const bf16x4*>(&Ps[wave][n16][s0]);
                pf[c][j4 * 4 + 0] = ph[0];
                pf[c][j4 * 4 + 1] = ph[1];
                pf[c][j4 * 4 + 2] = ph[2];
                pf[c][j4 * 4 + 3] = ph[3];
            }
        }

        // ---- O^T += V^T * P^T
        #pragma unroll
        for (int t = 0; t < 8; ++t) {
            floatx4 acc = o[t];
            #pragma unroll
            for (int c = 0; c < 2; ++c) {
                bf16x8 vf = *reinterpret_cast<const bf16x8*>(vl + t * 2048 + vfo[c]);
                acc = __builtin_amdgcn_mfma_f32_16x16x32_bf16(vf, pf[c], acc, 0, 0, 0);
            }
            o[t] = acc;
        }

        __syncthreads();   // readers of buf b done; DMA(kt+1) drained (implicit vmcnt(0))
    }

    // ---- epilogue: lane holds q = wave*16+n16, d = t*16 + quad*4 + {0..3}
    const float inv = 1.0f / l_i;
    const size_t rowoff = (size_t)(q0 + wave * 16 + n16) * DD;
    #pragma unroll
    for (int t = 0; t < 8; ++t) {
        float4 w;
        w.x = o[t][0] * inv; w.y = o[t][1] * inv;
        w.z = o[t][2] * inv; w.w = o[t][3] * inv;
        *reinterpret_cast<float4*>(ob + rowoff + t * 16 + quad * 4) = w;
    }
}

extern "C" void kernel_launch(void* const* d_in, const int* in_sizes, int n_in,
                              void* d_out, int out_size, void* d_ws, size_t ws_size,
                              hipStream_t stream) {
    const float* q = (const float*)d_in[0];
    const float* k = (const float*)d_in[1];
    const float* v = (const float*)d_in[2];
    float* out = (float*)d_out;

    bf16_t* kbf  = (bf16_t*)d_ws;
    bf16_t* vtbf = kbf + KV_ELEMS;
    prep_kv<<<dim3(SS / BN, BB * HH), 256, 0, stream>>>(k, v, kbf, vtbf);
    flexattn_fwd_bf16<<<dim3(SS / BM, BB * HH), 256, 0, stream>>>(q, kbf, vtbf, out);
}